// Round 20
// baseline (138.066 us; speedup 1.0000x reference)
//
#include <hip/hip_runtime.h>
#include <hip/hip_fp16.h>

// Truncated signature, depth=3, C=8, B=512, L=8192.
// Kernel 1 (R17/R18 pipeline + fp16 broadcast array):
//   one wave per (sample,chunk); lane (a,b)=(lane>>3,lane&7) owns S2[a][b],
//   S3[a][b][0..7]. Direct: S3[k] += cf*dx2[k][u], cf=S2+S1*db/2+da*db/6.
//   cf chain stays fp32 (da/db from fp32 Bc [c][t] stride 68, b128 reads).
//   Broadcast operand dx2[k][u] stored FP16: all 8 channels of a step = 16B
//   = ONE uniform ds_read_b128 (was two fp32 b128). Hot-loop DS/4-step block:
//   10 -> 6. Consume via fmaf(cf, __half2float(h), S3) -> v_fma_mix_f32.
//   A rows 16B, row-swizzle t' = t ^ ((t>>3)&7): staging ds_write_b16 spread
//   exactly 2-way across 32 banks (free); reads at compile-time offsets.
//   4-step blocks; block j+1 prefetched into named A/B register sets while
//   block j computes. launch_bounds(256,3) (tighter bounds caused spills).
// Kernel 2: per-sample in-order Chen combine of the G chunk signatures.

constexpr int B_ = 512;
constexpr int C_ = 8;
constexpr int L_ = 8192;
constexpr int NINC = L_ - 1;      // 8191 increments
constexpr int SIGDIM = 584;       // 8 + 64 + 512
constexpr int TILE = 64;          // steps per LDS tile
constexpr int BSTR = 68;          // Bc row stride (floats)
constexpr int AHN = 512;          // A: 64 rows x 8 halfs per wave
constexpr int BWSZ = C_ * BSTR;   // 544

__host__ __device__ constexpr int SW3(int t) { return t ^ ((t >> 3) & 7); }

struct __align__(16) h8v { __half2 a, b, c, d; };

// load block J's operands into register set SET (compile-time offsets)
#define LDP(SET, J)                                            \
  do {                                                         \
    SET##h0 = *(const h8v*)(ah + SW3((J) * 4 + 0) * 8);        \
    SET##h1 = *(const h8v*)(ah + SW3((J) * 4 + 1) * 8);        \
    SET##h2 = *(const h8v*)(ah + SW3((J) * 4 + 2) * 8);        \
    SET##h3 = *(const h8v*)(ah + SW3((J) * 4 + 3) * 8);        \
    SET##av = *(const float4*)(pa + (J) * 4);                  \
    SET##bv = *(const float4*)(pb + (J) * 4);                  \
  } while (0)

// one step on halved increments; fp32 chain; fp16 broadcast via fma_mix.
#define ST1(DA, DB, H)                                         \
  do {                                                         \
    const float w_ = __builtin_fmaf((DA), (2.f / 3.f), s1a);   \
    const float z_ = __builtin_fmaf((DA), (4.f / 3.f), s1a);   \
    const float cf = __builtin_fmaf((DB), w_, S2);             \
    S2  = __builtin_fmaf((DB), z_, cf);                        \
    s1a = __builtin_fmaf((DA), 2.f, s1a);                      \
    S3[0] = __builtin_fmaf(cf, __low2float((H).a),  S3[0]);    \
    S3[1] = __builtin_fmaf(cf, __high2float((H).a), S3[1]);    \
    S3[2] = __builtin_fmaf(cf, __low2float((H).b),  S3[2]);    \
    S3[3] = __builtin_fmaf(cf, __high2float((H).b), S3[3]);    \
    S3[4] = __builtin_fmaf(cf, __low2float((H).c),  S3[4]);    \
    S3[5] = __builtin_fmaf(cf, __high2float((H).c), S3[5]);    \
    S3[6] = __builtin_fmaf(cf, __low2float((H).d),  S3[6]);    \
    S3[7] = __builtin_fmaf(cf, __high2float((H).d), S3[7]);    \
  } while (0)

#define CB(SET)                                  \
  do {                                           \
    ST1(SET##av.x, SET##bv.x, SET##h0);          \
    ST1(SET##av.y, SET##bv.y, SET##h1);          \
    ST1(SET##av.z, SET##bv.z, SET##h2);          \
    ST1(SET##av.w, SET##bv.w, SET##h3);          \
  } while (0)

__global__ __launch_bounds__(256, 3)
void sig_chunks_kernel(const float* __restrict__ path, float* __restrict__ csig,
                       int G, int CPC) {
  __shared__ __align__(16) __half Ah[4][AHN];   // 4 KB total
  __shared__ __align__(16) float Bs[4][BWSZ];   // 8.7 KB
  const int wid  = __builtin_amdgcn_readfirstlane((int)(threadIdx.x >> 6));
  const int lane = (int)(threadIdx.x & 63);
  const int ia = lane >> 3;   // 'a' == staging channel
  const int ib = lane & 7;    // 'b' == staging position
  const int wglob = __builtin_amdgcn_readfirstlane((int)blockIdx.x) * 4 + wid;
  const int samp = wglob / G;
  const int g    = wglob - samp * G;
  const int ts = g * CPC;
  const int te = (ts + CPC < NINC) ? (ts + CPC) : NINC;   // exclusive end
  const float* pbase = path + (size_t)samp * (C_ * L_);
  const __half* ah = &Ah[wid][0];
  float* bs = Bs[wid];

  const int si = ib;
  const float* prow = pbase + ia * L_;
  const int grp = lane & ~7;
  const float* pa = bs + ia * BSTR;
  const float* pb = bs + ib * BSTR;

  // A-write pointers: step t stored at row t^((t>>3)&7), half-slot = channel.
  // d0 steps t = si*4+j (t>>3 == si>>1 for all j<4); d1 steps t = 32+si*4+j.
  __half* const ahw = &Ah[wid][0];
  const int q0_ = si >> 1;
  const int q1_ = (4 + q0_) & 7;
  __half* hw00 = ahw + (((si * 4 + 0) ^ q0_) * 8 + ia);
  __half* hw01 = ahw + (((si * 4 + 1) ^ q0_) * 8 + ia);
  __half* hw02 = ahw + (((si * 4 + 2) ^ q0_) * 8 + ia);
  __half* hw03 = ahw + (((si * 4 + 3) ^ q0_) * 8 + ia);
  __half* hw10 = ahw + ((32 + ((si * 4 + 0) ^ q1_)) * 8 + ia);
  __half* hw11 = ahw + ((32 + ((si * 4 + 1) ^ q1_)) * 8 + ia);
  __half* hw12 = ahw + ((32 + ((si * 4 + 2) ^ q1_)) * 8 + ia);
  __half* hw13 = ahw + ((32 + ((si * 4 + 3) ^ q1_)) * 8 + ia);

  float S3[8];
#pragma unroll
  for (int k = 0; k < 8; ++k) S3[k] = 0.f;
  float S2 = 0.f, s1a = 0.f;

  const int ntiles = (CPC + TILE - 1) / TILE;   // uniform across grid

  // prologue: prefetch tile 0 + boundary
  float4 r0 = *(const float4*)(prow + ts + si * 4);
  float4 r1 = *(const float4*)(prow + ts + 32 + si * 4);
  float bnd = prow[ts + TILE];

  h8v Ah0, Ah1, Ah2, Ah3;  float4 Aav, Abv;
  h8v Bh0, Bh1, Bh2, Bh3;  float4 Bav, Bbv;

  for (int tt = 0; tt < ntiles; ++tt) {
    const int t0 = ts + tt * TILE;
    const int cnt_ = te - t0;
    const int cnt = (cnt_ < TILE) ? cnt_ : TILE;

    // ---- stage tile tt: halved diffs -> Bc (fp32) + A (fp16, swizzled) ----
    {
      const float4 v0 = r0, v1 = r1;
      const float sA = __shfl(v0.x, lane + 1);
      const float sB = __shfl(v1.x, grp);
      const float sC = __shfl(v1.x, lane + 1);
      const float n0 = (si == 7) ? sB : sA;
      const float n1 = (si == 7) ? bnd : sC;
      float4 d0, d1;
      d0.x = (v0.y - v0.x) * 0.5f;
      d0.y = (v0.z - v0.y) * 0.5f;
      d0.z = (v0.w - v0.z) * 0.5f;
      d0.w = (n0 - v0.w) * 0.5f;
      d1.x = (v1.y - v1.x) * 0.5f;
      d1.y = (v1.z - v1.y) * 0.5f;
      d1.z = (v1.w - v1.z) * 0.5f;
      d1.w = (n1 - v1.w) * 0.5f;
      *(float4*)(bs + ia * BSTR + si * 4) = d0;
      *(float4*)(bs + ia * BSTR + 32 + si * 4) = d1;
      hw00[0] = __float2half(d0.x);
      hw01[0] = __float2half(d0.y);
      hw02[0] = __float2half(d0.z);
      hw03[0] = __float2half(d0.w);
      hw10[0] = __float2half(d1.x);
      hw11[0] = __float2half(d1.y);
      hw12[0] = __float2half(d1.z);
      hw13[0] = __float2half(d1.w);
    }

    // ---- prefetch tile tt+1 ----
    if (tt + 1 < ntiles) {
      const int t1g = t0 + TILE;
      r0 = *(const float4*)(prow + t1g + si * 4);
      r1 = *(const float4*)(prow + t1g + 32 + si * 4);
      const int bn = t1g + TILE;
      bnd = (bn < L_) ? prow[bn] : 0.f;
    }

    // ---- compute tile tt: 16 4-step blocks, A/B register double-buffer ----
    if (cnt == TILE) {
      LDP(A, 0);
#pragma unroll
      for (int jj = 0; jj < 8; ++jj) {
        LDP(B, 2 * jj + 1);
        CB(A);
        if (jj < 7) { LDP(A, 2 * jj + 2); }
        CB(B);
      }
    } else {
      // tail tile (only the last chunk's last tile, cnt=63): cold path,
      // full fp32 via Bc uniform b32 reads (no quantization here).
      for (int u = 0; u < cnt; ++u) {
        const float dav = pa[u];
        const float dbv = pb[u];
        const float w_ = __builtin_fmaf(dav, (2.f / 3.f), s1a);
        const float z_ = __builtin_fmaf(dav, (4.f / 3.f), s1a);
        const float cf = __builtin_fmaf(dbv, w_, S2);
        S2  = __builtin_fmaf(dbv, z_, cf);
        s1a = __builtin_fmaf(dav, 2.f, s1a);
#pragma unroll
        for (int k = 0; k < 8; ++k)
          S3[k] = __builtin_fmaf(cf, bs[k * BSTR + u], S3[k]);
      }
    }
  }

  float* cs = csig + ((size_t)samp * G + g) * SIGDIM;
  if (ib == 0) cs[ia] = s1a;
  cs[8 + lane] = S2;
  float4 o0, o1;
  o0.x = 2.f * S3[0]; o0.y = 2.f * S3[1]; o0.z = 2.f * S3[2]; o0.w = 2.f * S3[3];
  o1.x = 2.f * S3[4]; o1.y = 2.f * S3[5]; o1.z = 2.f * S3[6]; o1.w = 2.f * S3[7];
  *(float4*)(cs + 72 + lane * 8)     = o0;
  *(float4*)(cs + 72 + lane * 8 + 4) = o1;
}

__global__ __launch_bounds__(256)
void sig_combine_kernel(const float* __restrict__ csig, float* __restrict__ out, int G) {
  const int wid  = __builtin_amdgcn_readfirstlane((int)(threadIdx.x >> 6));
  const int lane = (int)(threadIdx.x & 63);
  const int ia = lane >> 3, ib = lane & 7;
  const int samp = __builtin_amdgcn_readfirstlane((int)blockIdx.x) * 4 + wid;
  const float* base = csig + (size_t)samp * G * SIGDIM;

  float R1a = base[ia];
  float R2  = base[8 + lane];
  float R3[8];
#pragma unroll
  for (int k = 0; k < 8; ++k) R3[k] = base[72 + lane * 8 + k];

  for (int g = 1; g < G; ++g) {
    const float* T = base + g * SIGDIM;
    float sT1[8];
#pragma unroll
    for (int k = 0; k < 8; ++k) sT1[k] = T[k];
    const float T1a  = T[ia];
    const float T1b  = T[ib];
    const float T2ab = T[8 + lane];
    float T2b[8], T3v[8];
#pragma unroll
    for (int k = 0; k < 8; ++k) T2b[k] = T[8 + ib * 8 + k];
#pragma unroll
    for (int k = 0; k < 8; ++k) T3v[k] = T[72 + lane * 8 + k];
    const float R1o = R1a, R2o = R2;
#pragma unroll
    for (int k = 0; k < 8; ++k)
      R3[k] += T3v[k] + R1o * T2b[k] + R2o * sT1[k];
    R2  += T2ab + R1o * T1b;
    R1a += T1a;
  }

  float* o = out + (size_t)samp * SIGDIM;
  if (ib == 0) o[ia] = R1a;
  o[8 + lane] = R2;
#pragma unroll
  for (int k = 0; k < 8; ++k) o[72 + lane * 8 + k] = R3[k];
}

extern "C" void kernel_launch(void* const* d_in, const int* in_sizes, int n_in,
                              void* d_out, int out_size, void* d_ws, size_t ws_size,
                              hipStream_t stream) {
  (void)in_sizes; (void)n_in; (void)out_size;
  const float* path = (const float*)d_in[0];
  float* out = (float*)d_out;
  float* ws  = (float*)d_ws;

  int G = 16;
  while (G > 1 && (size_t)B_ * G * SIGDIM * sizeof(float) > ws_size) G >>= 1;
  const int CPC = (NINC + G - 1) / G;   // increments per chunk

  sig_chunks_kernel<<<dim3(B_ * G / 4), dim3(256), 0, stream>>>(path, ws, G, CPC);
  sig_combine_kernel<<<dim3(B_ / 4), dim3(256), 0, stream>>>(ws, out, G);
}

// Round 22
// 66.402 us; speedup vs baseline: 2.0792x; 2.0792x over previous
//
#include <hip/hip_runtime.h>

// Truncated signature, depth=3, C=8, B=512, L=8192.
// Kernel 1 (MFMA rank-K restructure):
//   one wave per (sample,chunk); lane (a,b)=(lane>>3,lane&7) runs the cf chain
//   (fp32): cf = S2 + S1*db/2 + da*db/6. S3[ab][k] = sum_u cf[ab][u]*dx2[k][u]
//   is a GEMM (M=64 ab, N=8 k padded to 16, K=u) done on the MATRIX pipe:
//   per 32-step slice, cf -> fp16 (cvt_pkrtz; R20 proved fp16 operand safe,
//   absmax 4.0) -> swizzled LDS transpose -> 4x mfma_f32_16x16x32_f16 -> AGPR.
//   A/B fragments use symmetric k-mappings so any error in the assumed k-order
//   cancels; C/D mapping is the HW-verified one (col=lane&15,row=(l>>4)*4+j).
//   dx stored once as fp16 [16ch][64u] (XOR-swizzled 16B chunks, rows 8-15
//   zeroed once): serves chain reads (octet broadcast), B-fragments, staging.
//   dx zero-padded at step >= NINC -> no cold tail path at all.
// Kernel 2: per-sample in-order Chen combine of the G chunk signatures.

typedef _Float16 h8 __attribute__((ext_vector_type(8)));
typedef __fp16 fp16x2 __attribute__((ext_vector_type(2)));
typedef float f32x4 __attribute__((ext_vector_type(4)));

constexpr int B_ = 512;
constexpr int C_ = 8;
constexpr int L_ = 8192;
constexpr int NINC = L_ - 1;      // 8191 increments
constexpr int SIGDIM = 584;       // 8 + 64 + 512
constexpr int TILE = 64;          // steps per tile
constexpr int DXN = 16 * 64;      // DX: 16 rows x 64 halfs (2 KB)
constexpr int CFN = 64 * 32;      // CF: 64 rows x 32 halfs (4 KB)

static __device__ __forceinline__ float pkh(float a, float b) {
  fp16x2 r = __builtin_amdgcn_cvt_pkrtz(a, b);
  return __builtin_bit_cast(float, r);
}

struct __align__(8) f2w { float x, y; };

// one chain step j from av8/bv8 (fp16 halved increments), cf out (true scale)
#define STP(J, CF)                                            \
  do {                                                        \
    const float da = (float)av8[J];                           \
    const float db = (float)bv8[J];                           \
    const float w_ = __builtin_fmaf(da, (2.f / 3.f), s1a);    \
    const float z_ = __builtin_fmaf(da, (4.f / 3.f), s1a);    \
    (CF) = __builtin_fmaf(db, w_, S2);                        \
    S2  = __builtin_fmaf(db, z_, (CF));                       \
    s1a = __builtin_fmaf(da, 2.f, s1a);                       \
  } while (0)

// 8 chain steps at 16B-chunk KAPPA (= 4*slice + g4, compile-time), then pack
// cf to fp16 and write CF chunk (KAPPA&3) of this lane's row.
#define CHAIN8(KAPPA)                                                       \
  do {                                                                      \
    const h8 av8 = *(const h8*)(dxw + ia * 64 + 8 * ((KAPPA) ^ ia));        \
    const h8 bv8 = *(const h8*)(dxw + ib * 64 + 8 * ((KAPPA) ^ ib));        \
    float c0, c1, c2, c3, c4, c5, c6, c7;                                   \
    STP(0, c0); STP(1, c1); STP(2, c2); STP(3, c3);                         \
    STP(4, c4); STP(5, c5); STP(6, c6); STP(7, c7);                         \
    float4 wv;                                                              \
    wv.x = pkh(c0, c1); wv.y = pkh(c2, c3);                                 \
    wv.z = pkh(c4, c5); wv.w = pkh(c6, c7);                                 \
    *(float4*)(cfw + lane * 32 + 8 * (((KAPPA) & 3) ^ lq)) = wv;            \
  } while (0)

// 4 MFMAs for one 32-step slice; BFO = B-fragment offset for the slice.
#define SLICE_MMA(BFO)                                                      \
  do {                                                                      \
    const h8 bf  = *(const h8*)(dxw + (BFO));                               \
    const h8 a0f = *(const h8*)(cfw + cfo);                                 \
    const h8 a1f = *(const h8*)(cfw + cfo + 512);                           \
    const h8 a2f = *(const h8*)(cfw + cfo + 1024);                          \
    const h8 a3f = *(const h8*)(cfw + cfo + 1536);                          \
    acc0 = __builtin_amdgcn_mfma_f32_16x16x32_f16(a0f, bf, acc0, 0, 0, 0);  \
    acc1 = __builtin_amdgcn_mfma_f32_16x16x32_f16(a1f, bf, acc1, 0, 0, 0);  \
    acc2 = __builtin_amdgcn_mfma_f32_16x16x32_f16(a2f, bf, acc2, 0, 0, 0);  \
    acc3 = __builtin_amdgcn_mfma_f32_16x16x32_f16(a3f, bf, acc3, 0, 0, 0);  \
  } while (0)

__global__ __launch_bounds__(256, 3)
void sig_chunks_kernel(const float* __restrict__ path, float* __restrict__ csig,
                       int G, int CPC) {
  __shared__ __align__(16) _Float16 DXs[4][DXN];
  __shared__ __align__(16) _Float16 CFs[4][CFN];
  const int wid  = __builtin_amdgcn_readfirstlane((int)(threadIdx.x >> 6));
  const int lane = (int)(threadIdx.x & 63);
  const int ia = lane >> 3;   // 'a' == staging channel (0..7)
  const int ib = lane & 7;    // 'b' == staging position si
  const int wglob = __builtin_amdgcn_readfirstlane((int)blockIdx.x) * 4 + wid;
  const int samp = wglob / G;
  const int g    = wglob - samp * G;
  const int ts = g * CPC;
  const float* pbase = path + (size_t)samp * (C_ * L_);
  _Float16* dxw = &DXs[wid][0];
  _Float16* cfw = &CFs[wid][0];

  const int si = ib;
  const float* prow = pbase + ia * L_;
  const int grp = lane & ~7;
  const int lq = (lane >> 2) & 3;

  // per-lane constant offsets
  const int sto0 = ia * 64 + 8 * ((si >> 1) ^ ia) + (si & 1) * 4;        // d0
  const int sto1 = ia * 64 + 8 * ((4 + (si >> 1)) ^ ia) + (si & 1) * 4;  // d1
  const int cfo  = (lane & 15) * 32 + 8 * ((lane >> 4) ^ lq);            // A-frag
  const int bfo0 = (lane & 15) * 64 + 8 * ((0 + (lane >> 4)) ^ (lane & 7));
  const int bfo1 = (lane & 15) * 64 + 8 * ((4 + (lane >> 4)) ^ (lane & 7));

  // zero DX rows 8..15 once (zero-padding for the N=16 B operand)
  {
    const int zr = 8 + ia;
    *(float4*)(dxw + zr * 64 + 8 * (ib ^ (zr & 7))) = float4{0.f, 0.f, 0.f, 0.f};
  }

  f32x4 acc0 = {0.f, 0.f, 0.f, 0.f};
  f32x4 acc1 = {0.f, 0.f, 0.f, 0.f};
  f32x4 acc2 = {0.f, 0.f, 0.f, 0.f};
  f32x4 acc3 = {0.f, 0.f, 0.f, 0.f};
  float S2 = 0.f, s1a = 0.f;

  const int ntiles = CPC / TILE;   // CPC is a multiple of 64 for all G used

  // prologue: prefetch tile 0 + boundary
  float4 r0 = *(const float4*)(prow + ts + si * 4);
  float4 r1 = *(const float4*)(prow + ts + 32 + si * 4);
  int bi0 = ts + TILE; if (bi0 > NINC) bi0 = NINC;
  float bnd = prow[bi0];

  for (int tt = 0; tt < ntiles; ++tt) {
    const int t0 = ts + tt * TILE;

    // ---- stage tile tt: halved diffs -> fp16 DX (swizzled), masked at end ----
    {
      const float4 v0 = r0, v1 = r1;
      const float sA = __shfl(v0.x, lane + 1);
      const float sB = __shfl(v1.x, grp);
      const float sC = __shfl(v1.x, lane + 1);
      const float n0 = (si == 7) ? sB : sA;
      const float n1 = (si == 7) ? bnd : sC;
      float4 d0, d1;
      d0.x = (v0.y - v0.x) * 0.5f;
      d0.y = (v0.z - v0.y) * 0.5f;
      d0.z = (v0.w - v0.z) * 0.5f;
      d0.w = (n0 - v0.w) * 0.5f;
      d1.x = (v1.y - v1.x) * 0.5f;
      d1.y = (v1.z - v1.y) * 0.5f;
      d1.z = (v1.w - v1.z) * 0.5f;
      d1.w = (n1 - v1.w) * 0.5f;
      if (t0 + TILE > NINC) {   // only the last tile of the last chunk
        const int u0g = t0 + si * 4;
        if (u0g + 0 >= NINC) d0.x = 0.f;
        if (u0g + 1 >= NINC) d0.y = 0.f;
        if (u0g + 2 >= NINC) d0.z = 0.f;
        if (u0g + 3 >= NINC) d0.w = 0.f;
        if (u0g + 32 + 0 >= NINC) d1.x = 0.f;
        if (u0g + 32 + 1 >= NINC) d1.y = 0.f;
        if (u0g + 32 + 2 >= NINC) d1.z = 0.f;
        if (u0g + 32 + 3 >= NINC) d1.w = 0.f;
      }
      f2w w0; w0.x = pkh(d0.x, d0.y); w0.y = pkh(d0.z, d0.w);
      f2w w1; w1.x = pkh(d1.x, d1.y); w1.y = pkh(d1.z, d1.w);
      *(f2w*)(dxw + sto0) = w0;
      *(f2w*)(dxw + sto1) = w1;
    }

    // ---- prefetch tile tt+1 ----
    if (tt + 1 < ntiles) {
      const int t1g = t0 + TILE;
      r0 = *(const float4*)(prow + t1g + si * 4);
      r1 = *(const float4*)(prow + t1g + 32 + si * 4);
      int bn = t1g + TILE; if (bn > NINC) bn = NINC;
      bnd = prow[bn];
    }

    // ---- slice 0: steps 0..31 ----
    CHAIN8(0); CHAIN8(1); CHAIN8(2); CHAIN8(3);
    SLICE_MMA(bfo0);
    // ---- slice 1: steps 32..63 ----
    CHAIN8(4); CHAIN8(5); CHAIN8(6); CHAIN8(7);
    SLICE_MMA(bfo1);
  }

  // ---- epilogue ----
  float* cs = csig + ((size_t)samp * G + g) * SIGDIM;
  if (ib == 0) cs[ia] = s1a;
  cs[8 + lane] = S2;
  // MFMA D mapping (HW-verified): lane holds D[row=(l>>4)*4+j][col=l&15],
  // m-tile m -> ab = 16m + row; k = col (valid k < 8). x2 undoes dx halving.
  if ((lane & 15) < 8) {
    const int rb = 4 * (lane >> 4);
    const int kk = lane & 15;
    float* s3 = cs + 72;
    s3[(rb + 0) * 8 + kk]      = 2.f * acc0[0];
    s3[(rb + 1) * 8 + kk]      = 2.f * acc0[1];
    s3[(rb + 2) * 8 + kk]      = 2.f * acc0[2];
    s3[(rb + 3) * 8 + kk]      = 2.f * acc0[3];
    s3[(16 + rb + 0) * 8 + kk] = 2.f * acc1[0];
    s3[(16 + rb + 1) * 8 + kk] = 2.f * acc1[1];
    s3[(16 + rb + 2) * 8 + kk] = 2.f * acc1[2];
    s3[(16 + rb + 3) * 8 + kk] = 2.f * acc1[3];
    s3[(32 + rb + 0) * 8 + kk] = 2.f * acc2[0];
    s3[(32 + rb + 1) * 8 + kk] = 2.f * acc2[1];
    s3[(32 + rb + 2) * 8 + kk] = 2.f * acc2[2];
    s3[(32 + rb + 3) * 8 + kk] = 2.f * acc2[3];
    s3[(48 + rb + 0) * 8 + kk] = 2.f * acc3[0];
    s3[(48 + rb + 1) * 8 + kk] = 2.f * acc3[1];
    s3[(48 + rb + 2) * 8 + kk] = 2.f * acc3[2];
    s3[(48 + rb + 3) * 8 + kk] = 2.f * acc3[3];
  }
}

__global__ __launch_bounds__(256)
void sig_combine_kernel(const float* __restrict__ csig, float* __restrict__ out, int G) {
  const int wid  = __builtin_amdgcn_readfirstlane((int)(threadIdx.x >> 6));
  const int lane = (int)(threadIdx.x & 63);
  const int ia = lane >> 3, ib = lane & 7;
  const int samp = __builtin_amdgcn_readfirstlane((int)blockIdx.x) * 4 + wid;
  const float* base = csig + (size_t)samp * G * SIGDIM;

  float R1a = base[ia];
  float R2  = base[8 + lane];
  float R3[8];
#pragma unroll
  for (int k = 0; k < 8; ++k) R3[k] = base[72 + lane * 8 + k];

  for (int g = 1; g < G; ++g) {
    const float* T = base + g * SIGDIM;
    float sT1[8];
#pragma unroll
    for (int k = 0; k < 8; ++k) sT1[k] = T[k];
    const float T1a  = T[ia];
    const float T1b  = T[ib];
    const float T2ab = T[8 + lane];
    float T2b[8], T3v[8];
#pragma unroll
    for (int k = 0; k < 8; ++k) T2b[k] = T[8 + ib * 8 + k];
#pragma unroll
    for (int k = 0; k < 8; ++k) T3v[k] = T[72 + lane * 8 + k];
    const float R1o = R1a, R2o = R2;
#pragma unroll
    for (int k = 0; k < 8; ++k)
      R3[k] += T3v[k] + R1o * T2b[k] + R2o * sT1[k];
    R2  += T2ab + R1o * T1b;
    R1a += T1a;
  }

  float* o = out + (size_t)samp * SIGDIM;
  if (ib == 0) o[ia] = R1a;
  o[8 + lane] = R2;
#pragma unroll
  for (int k = 0; k < 8; ++k) o[72 + lane * 8 + k] = R3[k];
}

extern "C" void kernel_launch(void* const* d_in, const int* in_sizes, int n_in,
                              void* d_out, int out_size, void* d_ws, size_t ws_size,
                              hipStream_t stream) {
  (void)in_sizes; (void)n_in; (void)out_size;
  const float* path = (const float*)d_in[0];
  float* out = (float*)d_out;
  float* ws  = (float*)d_ws;

  int G = 16;
  while (G > 1 && (size_t)B_ * G * SIGDIM * sizeof(float) > ws_size) G >>= 1;
  const int CPC = (NINC + G - 1) / G;   // multiple of 64 for G in {16,8,4,2,1}

  sig_chunks_kernel<<<dim3(B_ * G / 4), dim3(256), 0, stream>>>(path, ws, G, CPC);
  sig_combine_kernel<<<dim3(B_ / 4), dim3(256), 0, stream>>>(ws, out, G);
}